// Round 1
// baseline (118.546 us; speedup 1.0000x reference)
//
#include <hip/hip_runtime.h>

#define D_DIM 512

__device__ __forceinline__ float flog2(float x) {
    return __builtin_amdgcn_logf(x);   // v_log_f32 (= log2); inputs >= ~4e-6, no denormal wrapper
}

// ============ per-row sums: E[row] = sum_d x*log2(x). One wave/row, 4 rows/block ============
__global__ __launch_bounds__(256)
void jsd_entropy_kernel(const float* __restrict__ a,
                        const float* __restrict__ b,
                        float* __restrict__ E, int N, int M) {
    const int wave = threadIdx.x >> 6;
    const int lane = threadIdx.x & 63;
    const int row = blockIdx.x * 4 + wave;
    if (row >= N + M) return;
    const float* src = (row < N) ? (a + (size_t)row * D_DIM)
                                 : (b + (size_t)(row - N) * D_DIM);
    const float4* s4 = (const float4*)src;
    float4 v0 = s4[lane];
    float4 v1 = s4[lane + 64];
    float s = 0.f;
    s = fmaf(v0.x, flog2(v0.x), s);
    s = fmaf(v0.y, flog2(v0.y), s);
    s = fmaf(v0.z, flog2(v0.z), s);
    s = fmaf(v0.w, flog2(v0.w), s);
    s = fmaf(v1.x, flog2(v1.x), s);
    s = fmaf(v1.y, flog2(v1.y), s);
    s = fmaf(v1.z, flog2(v1.z), s);
    s = fmaf(v1.w, flog2(v1.w), s);
#pragma unroll
    for (int off = 32; off > 0; off >>= 1) s += __shfl_down(s, off, 64);
    if (lane == 0) E[row] = s;
}

// ============ main: out[i,j] = 1 + 0.5*(Ea[i]+Eb[j]) - 0.5*sum_d t*log2(t), t=a+b ============
constexpr int TR = 64;           // A-rows per block
constexpr int TC = 32;           // B-cols per block
constexpr int DK = 64;           // d per chunk
constexpr int NCH = D_DIM / DK;  // 8

// Stage a ROWS x DK f32 tile (global row stride D_DIM) into LDS [ROWS][DK] via
// global_load_lds dwordx4. LDS dest is linear; the XOR swizzle
//   LDS[r][16B-chunk c] = global chunk (c ^ ((r>>2)&15))
// is applied by pre-swizzling the per-lane GLOBAL source address (guide §5/m173).
// Each call moves 4 rows (64 lanes x 16B); wave w owns rows [w*ROWS/4, (w+1)*ROWS/4).
template<int ROWS>
__device__ __forceinline__ void stage_tile(const float* __restrict__ g,
                                           float* lbuf, int w, int l) {
#pragma unroll
    for (int k = 0; k < ROWS / 16; ++k) {
        const int r0  = w * (ROWS / 4) + k * 4;
        const int swz = (r0 >> 2) & 15;            // constant per 4-row call
        const int r   = r0 + (l >> 4);
        const int c   = (l & 15) ^ swz;
        const float* gp = g + (size_t)r * D_DIM + 4 * c;
        __builtin_amdgcn_global_load_lds(
            (const __attribute__((address_space(1))) void*)gp,
            (__attribute__((address_space(3))) void*)(lbuf + r0 * DK),
            16, 0, 0);
    }
}

__global__ __launch_bounds__(256)
void jsd_main_kernel(const float* __restrict__ a, const float* __restrict__ b,
                     const float* __restrict__ Ea, const float* __restrict__ Eb,
                     float* __restrict__ out, int N, int M) {
    __shared__ __align__(16) float As[2][TR][DK];   // 32 KB
    __shared__ __align__(16) float Bs[2][TC][DK];   // 16 KB

    const int tid = threadIdx.x;
    const int tx = tid & 15;       // -> cols tx*2 + {0,1}
    const int ty = tid >> 4;       // -> rows ty*4 + {0..3}
    const int w  = tid >> 6;
    const int l  = tid & 63;
    const int rowBase = blockIdx.y * TR;
    const int colBase = blockIdx.x * TC;

    const float* aT = a + (size_t)rowBase * D_DIM;
    const float* bT = b + (size_t)colBase * D_DIM;

    float acc[4][2] = {};

    stage_tile<TR>(aT, &As[0][0][0], w, l);
    stage_tile<TC>(bT, &Bs[0][0][0], w, l);

#pragma unroll 1
    for (int ck = 0; ck < NCH; ++ck) {
        const int cur = ck & 1;
        asm volatile("s_waitcnt vmcnt(0)" ::: "memory");  // staged chunk landed in LDS
        __syncthreads();
        if (ck + 1 < NCH) {   // issue next chunk's loads; they fly under this chunk's compute
            stage_tile<TR>(aT + (ck + 1) * DK, &As[cur ^ 1][0][0], w, l);
            stage_tile<TC>(bT + (ck + 1) * DK, &Bs[cur ^ 1][0][0], w, l);
        }
        __builtin_amdgcn_sched_barrier(0);  // keep load-issue ahead of compute

#pragma unroll 4
        for (int q0 = 0; q0 < 16; ++q0) {
            // read swizzle matches stage-side: chunk ^= (row>>2)&15
            const int ca = ((q0 ^ ty) << 2);          // A rows 4ty+rr: (row>>2)=ty
            const int cb = ((q0 ^ (tx >> 1)) << 2);   // B rows 2tx+cc: (row>>2)=tx>>1
            float4 av[4], bv[2];
#pragma unroll
            for (int rr = 0; rr < 4; ++rr)
                av[rr] = *(const float4*)&As[cur][ty * 4 + rr][ca];
#pragma unroll
            for (int cc = 0; cc < 2; ++cc)
                bv[cc] = *(const float4*)&Bs[cur][tx * 2 + cc][cb];
#pragma unroll
            for (int rr = 0; rr < 4; ++rr)
#pragma unroll
                for (int cc = 0; cc < 2; ++cc) {
                    float t0 = av[rr].x + bv[cc].x;
                    float t1 = av[rr].y + bv[cc].y;
                    float t2 = av[rr].z + bv[cc].z;
                    float t3 = av[rr].w + bv[cc].w;
                    float s = acc[rr][cc];
                    s = fmaf(t0, flog2(t0), s);
                    s = fmaf(t1, flog2(t1), s);
                    s = fmaf(t2, flog2(t2), s);
                    s = fmaf(t3, flog2(t3), s);
                    acc[rr][cc] = s;
                }
        }
    }

    // epilogue: direct stores (no atomics, no memset)
    const float2 ebv = *(const float2*)(Eb + colBase + tx * 2);
#pragma unroll
    for (int rr = 0; rr < 4; ++rr) {
        const int i = rowBase + ty * 4 + rr;
        const float base = 1.0f + 0.5f * Ea[i];
        float2 v;
        v.x = fmaf(-0.5f, acc[rr][0], base + 0.5f * ebv.x);
        v.y = fmaf(-0.5f, acc[rr][1], base + 0.5f * ebv.y);
        *(float2*)(out + (size_t)i * M + colBase + tx * 2) = v;
    }
}

extern "C" void kernel_launch(void* const* d_in, const int* in_sizes, int n_in,
                              void* d_out, int out_size, void* d_ws, size_t ws_size,
                              hipStream_t stream) {
    const float* a = (const float*)d_in[0];
    const float* b = (const float*)d_in[1];
    const int N = in_sizes[0] / D_DIM;   // 1024
    const int M = in_sizes[1] / D_DIM;   // 1024
    float* E = (float*)d_ws;             // Ea[0..N), Eb[N..N+M)

    jsd_entropy_kernel<<<(N + M + 3) / 4, 256, 0, stream>>>(a, b, E, N, M);

    dim3 grid(M / TC, N / TR);           // 32 x 16 = 512 blocks -> 2 blocks/CU
    jsd_main_kernel<<<grid, 256, 0, stream>>>(a, b, E, E + N, (float*)d_out, N, M);
}